// Round 2
// baseline (1427.527 us; speedup 1.0000x reference)
//
#include <hip/hip_runtime.h>
#include <stdint.h>

// ---- sizes ----
#define T_TOK 8192      // B*L = 4*2048
#define SEQL  2048
#define DM    1024
#define DI    2048
#define DSTATE 128
#define NH    32
#define HD    64
#define CONVD 2304      // DI + 2*DSTATE
#define DINP  4384      // 2*DI + 2*DSTATE + NH
#define LD_ZX 4480      // DINP padded to multiple of 128

typedef __attribute__((ext_vector_type(8))) __bf16 bfrag;
typedef __attribute__((ext_vector_type(8))) short s16x8;
typedef __attribute__((ext_vector_type(4))) float f32x4;

__device__ __forceinline__ float bf2f(unsigned short u){
  return __uint_as_float(((unsigned)u) << 16);
}
__device__ __forceinline__ unsigned short f2bf(float f){
  unsigned u = __float_as_uint(f);
  unsigned r = (u + 0x7FFFu + ((u >> 16) & 1u)) >> 16;   // RNE
  return (unsigned short)r;
}

__device__ __forceinline__ void gl_lds16(const unsigned short* g, unsigned short* l){
  __builtin_amdgcn_global_load_lds(
      (const __attribute__((address_space(1))) void*)g,
      (__attribute__((address_space(3))) void*)l,
      16, 0, 0);
}

// ---- weight f32 -> bf16 (with zero-pad tail for in_proj) ----
__global__ __launch_bounds__(256) void cvt_w_kernel(const float* __restrict__ src,
                                                    unsigned short* __restrict__ dst,
                                                    int n4, int srcn4){
  int i = blockIdx.x * 256 + threadIdx.x;
  if (i >= n4) return;
  ushort4 o;
  if (i < srcn4){
    float4 v = ((const float4*)src)[i];
    o.x = f2bf(v.x); o.y = f2bf(v.y); o.z = f2bf(v.z); o.w = f2bf(v.w);
  } else {
    o.x = o.y = o.z = o.w = 0;
  }
  *(ushort4*)(dst + (size_t)i * 4) = o;
}

// ---- rmsnorm(h_prev) | rmsnorm(emb_next) -> combined (T x 2048) bf16 ----
__global__ __launch_bounds__(256) void rmsnorm2_kernel(const float* __restrict__ a,
                                                       const float* __restrict__ b,
                                                       const float* __restrict__ w,
                                                       unsigned short* __restrict__ out){
  int t = blockIdx.x, tid = threadIdx.x;
  float4 va = *(const float4*)(a + (size_t)t * DM + tid * 4);
  float4 vb = *(const float4*)(b + (size_t)t * DM + tid * 4);
  float sa = va.x*va.x + va.y*va.y + va.z*va.z + va.w*va.w;
  float sb = vb.x*vb.x + vb.y*vb.y + vb.z*vb.z + vb.w*vb.w;
  #pragma unroll
  for (int o = 32; o; o >>= 1){ sa += __shfl_down(sa, o); sb += __shfl_down(sb, o); }
  __shared__ float reda[4], redb[4];
  int wv = tid >> 6, lane = tid & 63;
  if (!lane){ reda[wv] = sa; redb[wv] = sb; }
  __syncthreads();
  float ta = reda[0] + reda[1] + reda[2] + reda[3];
  float tb = redb[0] + redb[1] + redb[2] + redb[3];
  float ra = rsqrtf(ta * (1.f/1024.f) + 1e-6f);
  float rb = rsqrtf(tb * (1.f/1024.f) + 1e-6f);
  float4 vw = *(const float4*)(w + tid * 4);
  unsigned short* o0 = out + (size_t)t * DI + tid * 4;
  o0[0] = f2bf(va.x*ra*vw.x); o0[1] = f2bf(va.y*ra*vw.y);
  o0[2] = f2bf(va.z*ra*vw.z); o0[3] = f2bf(va.w*ra*vw.w);
  unsigned short* o1 = o0 + DM;
  o1[0] = f2bf(vb.x*rb*vw.x); o1[1] = f2bf(vb.y*rb*vw.y);
  o1[2] = f2bf(vb.z*rb*vw.z); o1[3] = f2bf(vb.w*rb*vw.w);
}

// ---- bf16 GEMM: C[M,ldc] = A[M,K] @ W[N,K]^T (+bias), 128x128 tile, BK=64 ----
template<bool F32OUT>
__global__ __launch_bounds__(256) void gemm_bf16_kernel(const unsigned short* __restrict__ A,
                                                        const unsigned short* __restrict__ W,
                                                        void* __restrict__ Cv,
                                                        const float* __restrict__ bias,
                                                        int M, int N, int K, int ldc){
  __shared__ unsigned short As[128 * 64];
  __shared__ unsigned short Bs[128 * 64];
  const int nN = N >> 7;
  const int bid = blockIdx.x;
  const int tm = bid / nN, tn = bid % nN;
  const int tid = threadIdx.x;
  const int wv = tid >> 6, lane = tid & 63;
  const int wm = wv >> 1, wn = wv & 1;
  const int rA = lane >> 3;            // 0..7
  const int cA = (lane & 7) << 3;      // 0,8,..,56
  const size_t arow0 = (size_t)(tm * 128) * K;
  const size_t brow0 = (size_t)(tn * 128) * K;

  f32x4 zero4 = {0.f, 0.f, 0.f, 0.f};
  f32x4 acc[4][4];
  #pragma unroll
  for (int i = 0; i < 4; ++i)
    #pragma unroll
    for (int j = 0; j < 4; ++j) acc[i][j] = zero4;

  const int nK = K >> 6;
  for (int kt = 0; kt < nK; ++kt){
    const int k0 = kt << 6;
    if (kt) __syncthreads();
    #pragma unroll
    for (int i = 0; i < 4; ++i){
      int base = (wv * 4 + i) * 8;      // 8 rows per issue
      gl_lds16(A + arow0 + (size_t)(base + rA) * K + k0 + cA, &As[base * 64]);
      gl_lds16(W + brow0 + (size_t)(base + rA) * K + k0 + cA, &Bs[base * 64]);
    }
    __syncthreads();   // compiler drains vmcnt before s_barrier
    #pragma unroll
    for (int kk = 0; kk < 2; ++kk){
      const int ko = kk * 32 + (lane >> 4) * 8;
      bfrag af[4], bfv[4];
      #pragma unroll
      for (int f = 0; f < 4; ++f){
        af[f]  = *reinterpret_cast<const bfrag*>(&As[(wm*64 + f*16 + (lane & 15)) * 64 + ko]);
        bfv[f] = *reinterpret_cast<const bfrag*>(&Bs[(wn*64 + f*16 + (lane & 15)) * 64 + ko]);
      }
      #pragma unroll
      for (int fm = 0; fm < 4; ++fm)
        #pragma unroll
        for (int fn = 0; fn < 4; ++fn)
          acc[fm][fn] = __builtin_amdgcn_mfma_f32_16x16x32_bf16(af[fm], bfv[fn], acc[fm][fn], 0, 0, 0);
    }
  }
  // epilogue: C/D layout col=lane&15, row=(lane>>4)*4+r
  const int r0 = (lane >> 4) * 4, ci = lane & 15;
  #pragma unroll
  for (int fm = 0; fm < 4; ++fm){
    #pragma unroll
    for (int fn = 0; fn < 4; ++fn){
      int col = tn*128 + wn*64 + fn*16 + ci;
      float bv = bias ? bias[col] : 0.f;
      #pragma unroll
      for (int r = 0; r < 4; ++r){
        int row = tm*128 + wm*64 + fm*16 + r0 + r;
        float val = acc[fm][fn][r] + bv;
        if (F32OUT) ((float*)Cv)[(size_t)row * ldc + col] = val;
        else        ((unsigned short*)Cv)[(size_t)row * ldc + col] = f2bf(val);
      }
    }
  }
}

// ---- causal depthwise conv(4) + bias + silu over xBC section of zx ----
__global__ __launch_bounds__(256) void conv_kernel(const unsigned short* __restrict__ zx,
                                                   const float* __restrict__ cw,
                                                   const float* __restrict__ cb,
                                                   unsigned short* __restrict__ xbc){
  int c = blockIdx.x * 256 + threadIdx.x;   // 0..2303
  int t = blockIdx.y;                        // 0..8191
  int l = t & (SEQL - 1);
  const unsigned short* base = zx + (size_t)t * LD_ZX + DI + c;
  float acc = cb[c];
  float w0 = cw[c*4+0], w1 = cw[c*4+1], w2 = cw[c*4+2], w3 = cw[c*4+3];
  if (l >= 3) acc += w0 * bf2f(*(base - 3 * LD_ZX));
  if (l >= 2) acc += w1 * bf2f(*(base - 2 * LD_ZX));
  if (l >= 1) acc += w2 * bf2f(*(base - 1 * LD_ZX));
  acc += w3 * bf2f(*base);
  float s = acc / (1.f + expf(-acc));        // silu
  xbc[(size_t)t * CONVD + c] = f2bf(s);
}

// ---- dt = softplus(dt_raw + bias); dA = exp(dt * -exp(A_log)) ----
__global__ __launch_bounds__(256) void dt_kernel(const unsigned short* __restrict__ zx,
                                                 const float* __restrict__ dtbias,
                                                 const float* __restrict__ alog,
                                                 float* __restrict__ dtb,
                                                 float* __restrict__ dab){
  int i = blockIdx.x * 256 + threadIdx.x;    // T*32
  int t = i >> 5, h = i & 31;
  float xr = bf2f(zx[(size_t)t * LD_ZX + 4352 + h]) + dtbias[h];
  float dt = (xr > 20.f) ? xr : log1pf(expf(xr));
  float A = -expf(alog[h]);
  dtb[i] = dt;
  dab[i] = expf(dt * A);
}

// ---- sequential SSM scan; 256 blocks = (b, h, p-half); state in registers ----
__global__ __launch_bounds__(256) void scan_kernel(const unsigned short* __restrict__ xbc,
                                                   const float* __restrict__ dtb,
                                                   const float* __restrict__ dab,
                                                   const float* __restrict__ Dvec,
                                                   unsigned short* __restrict__ yout){
  int blk = blockIdx.x;                 // 4b * 32h * 2ph
  int b = blk >> 6; int rem = blk & 63; int h = rem >> 1; int ph = rem & 1;
  int tid = threadIdx.x;
  int pi = tid >> 3;                    // 0..31
  int q  = tid & 7;                     // 0..7
  int p  = ph * 32 + pi;
  int n0 = q * 16;
  float st[16];
  #pragma unroll
  for (int j = 0; j < 16; ++j) st[j] = 0.f;
  float Dh = Dvec[h];
  size_t tokBase = (size_t)b * SEQL;
  const unsigned short* pB = xbc + tokBase * CONVD + DI + n0;
  const unsigned short* pC = xbc + tokBase * CONVD + DI + DSTATE + n0;
  const unsigned short* pX = xbc + tokBase * CONVD + h * HD + p;
  const float* pdt = dtb + tokBase * NH + h;
  const float* pdA = dab + tokBase * NH + h;

  s16x8 B0 = *(const s16x8*)pB,      B1 = *(const s16x8*)(pB + 8);
  s16x8 C0 = *(const s16x8*)pC,      C1 = *(const s16x8*)(pC + 8);
  float xv  = bf2f(pX[0]);
  float dtv = pdt[0], dAv = pdA[0];

  for (int t = 0; t < SEQL; ++t){
    int tn = (t + 1) & (SEQL - 1);    // wraps; last prefetch harmless
    size_t onx = (size_t)tn * CONVD;
    s16x8 nB0 = *(const s16x8*)(pB + onx), nB1 = *(const s16x8*)(pB + onx + 8);
    s16x8 nC0 = *(const s16x8*)(pC + onx), nC1 = *(const s16x8*)(pC + onx + 8);
    float nx  = bf2f(pX[onx]);
    float ndt = pdt[(size_t)tn * NH], ndA = pdA[(size_t)tn * NH];

    float c1 = dtv * xv;
    float accp = 0.f;
    #pragma unroll
    for (int j = 0; j < 8; ++j){
      float bj = bf2f((unsigned short)B0[j]);
      float cj = bf2f((unsigned short)C0[j]);
      st[j] = fmaf(st[j], dAv, c1 * bj);
      accp = fmaf(st[j], cj, accp);
    }
    #pragma unroll
    for (int j = 0; j < 8; ++j){
      float bj = bf2f((unsigned short)B1[j]);
      float cj = bf2f((unsigned short)C1[j]);
      st[8+j] = fmaf(st[8+j], dAv, c1 * bj);
      accp = fmaf(st[8+j], cj, accp);
    }
    accp += __shfl_xor(accp, 1);
    accp += __shfl_xor(accp, 2);
    accp += __shfl_xor(accp, 4);
    if (q == 0)
      yout[(tokBase + t) * DI + h * HD + p] = f2bf(accp + Dh * xv);

    B0 = nB0; B1 = nB1; C0 = nC0; C1 = nC1; xv = nx; dtv = ndt; dAv = ndA;
  }
}

// ---- gated RMSNorm: out = gw * normalize(y * silu(z)); safe in-place on y ----
__global__ __launch_bounds__(256) void gated_kernel(const unsigned short* __restrict__ y,
                                                    const unsigned short* __restrict__ zx,
                                                    const float* __restrict__ gw,
                                                    unsigned short* __restrict__ out){
  int t = blockIdx.x, tid = threadIdx.x;
  s16x8 yv = *(const s16x8*)(y  + (size_t)t * DI    + tid * 8);
  s16x8 zv = *(const s16x8*)(zx + (size_t)t * LD_ZX + tid * 8);
  float g[8]; float ss = 0.f;
  #pragma unroll
  for (int j = 0; j < 8; ++j){
    float yf = bf2f((unsigned short)yv[j]);
    float zf = bf2f((unsigned short)zv[j]);
    float gi = yf * (zf / (1.f + expf(-zf)));
    g[j] = gi; ss += gi * gi;
  }
  #pragma unroll
  for (int o = 32; o; o >>= 1) ss += __shfl_down(ss, o);
  __shared__ float red[4];
  int wv = tid >> 6, lane = tid & 63;
  if (!lane) red[wv] = ss;
  __syncthreads();
  float tot = red[0] + red[1] + red[2] + red[3];
  float sc = rsqrtf(tot * (1.f/2048.f) + 1e-5f);
  unsigned short* o0 = out + (size_t)t * DI + tid * 8;
  #pragma unroll
  for (int j = 0; j < 8; ++j) o0[j] = f2bf(g[j] * sc * gw[tid * 8 + j]);
}

// ---- dec: output[t,v] = h_k[t,:] . dec_W[v,:] + dec_b[v]; one wave per dot ----
__global__ __launch_bounds__(256) void dec_kernel(const float* __restrict__ hk,
                                                  const float* __restrict__ dw,
                                                  const float* __restrict__ db,
                                                  float* __restrict__ out){
  int gwv = (blockIdx.x * 256 + threadIdx.x) >> 6;  // 0..24575
  int lane = threadIdx.x & 63;
  int t = gwv / 3, v = gwv - t * 3;
  const float* hr = hk + (size_t)t * DM + lane * 16;
  const float* wr = dw + v * DM + lane * 16;
  float acc = 0.f;
  #pragma unroll
  for (int j = 0; j < 16; ++j) acc = fmaf(hr[j], wr[j], acc);
  #pragma unroll
  for (int o = 32; o; o >>= 1) acc += __shfl_down(acc, o);
  if (!lane) out[t * 3 + v] = acc + db[v];
}

extern "C" void kernel_launch(void* const* d_in, const int* in_sizes, int n_in,
                              void* d_out, int out_size, void* d_ws, size_t ws_size,
                              hipStream_t stream){
  const float* h_prev    = (const float*)d_in[0];
  const float* emb_next  = (const float*)d_in[1];
  const float* norm_w    = (const float*)d_in[2];
  const float* proj_W    = (const float*)d_in[3];
  const float* proj_b    = (const float*)d_in[4];
  const float* in_proj_W = (const float*)d_in[5];
  const float* conv_w    = (const float*)d_in[6];
  const float* conv_b    = (const float*)d_in[7];
  const float* dt_bias   = (const float*)d_in[8];
  const float* A_log     = (const float*)d_in[9];
  const float* Dvec      = (const float*)d_in[10];
  const float* gnorm_w   = (const float*)d_in[11];
  const float* out_proj_W= (const float*)d_in[12];
  const float* dec_W     = (const float*)d_in[13];
  const float* dec_b     = (const float*)d_in[14];

  char* ws = (char*)d_ws;
  size_t off = 0;
  auto take = [&](size_t bytes){ char* p = ws + off; off += (bytes + 255) & ~(size_t)255; return p; };
  unsigned short* wproj = (unsigned short*)take((size_t)DM * DI * 2);
  unsigned short* winp  = (unsigned short*)take((size_t)LD_ZX * DM * 2);
  unsigned short* wout  = (unsigned short*)take((size_t)DM * DI * 2);
  unsigned short* zx    = (unsigned short*)take((size_t)T_TOK * LD_ZX * 2);
  float*          dtb   = (float*)take((size_t)T_TOK * NH * 4);
  float*          dab   = (float*)take((size_t)T_TOK * NH * 4);
  // region A: combined(32MB) + hprime(16MB); later overlaid by xbc(36MB)
  char* regionA = take((size_t)T_TOK * DI * 2 + (size_t)T_TOK * DM * 2);
  unsigned short* combined = (unsigned short*)regionA;
  unsigned short* hprime   = (unsigned short*)(regionA + (size_t)T_TOK * DI * 2);
  unsigned short* xbc      = (unsigned short*)regionA;           // overlays dead combined+hprime
  unsigned short* ybuf     = (unsigned short*)take((size_t)T_TOK * DI * 2);  // gated in-place

  float* outp = (float*)d_out;                   // [T*3] output, then [T*1024] h_k (f32!)
  float* hk   = outp + (size_t)T_TOK * 3;

  // 1) weights -> bf16 (in_proj padded 4384->4480 rows with zeros)
  cvt_w_kernel<<<2048, 256, 0, stream>>>(proj_W, wproj, DM*DI/4, DM*DI/4);
  cvt_w_kernel<<<4480, 256, 0, stream>>>(in_proj_W, winp, LD_ZX*DM/4, DINP*DM/4);
  cvt_w_kernel<<<2048, 256, 0, stream>>>(out_proj_W, wout, DM*DI/4, DM*DI/4);

  // 2) dual rmsnorm -> combined (T x 2048)
  rmsnorm2_kernel<<<T_TOK, 256, 0, stream>>>(h_prev, emb_next, norm_w, combined);

  // 3) h_prime = combined @ proj_W^T + proj_b   (M=8192,N=1024,K=2048)
  gemm_bf16_kernel<false><<<(T_TOK/128)*(DM/128), 256, 0, stream>>>(combined, wproj, hprime, proj_b,
                                                                    T_TOK, DM, DI, DM);
  // 4) zxbcdt = h_prime @ in_proj_W^T           (M=8192,N=4480,K=1024)
  gemm_bf16_kernel<false><<<(T_TOK/128)*(LD_ZX/128), 256, 0, stream>>>(hprime, winp, zx, nullptr,
                                                                       T_TOK, LD_ZX, DM, LD_ZX);
  // 5) conv + silu on xBC  (xbc overlays combined/hprime which are now dead)
  conv_kernel<<<dim3(CONVD/256, T_TOK), 256, 0, stream>>>(zx, conv_w, conv_b, xbc);
  // 6) dt / dA
  dt_kernel<<<T_TOK*NH/256, 256, 0, stream>>>(zx, dt_bias, A_log, dtb, dab);
  // 7) SSM scan -> y (+ D*x)
  scan_kernel<<<256, 256, 0, stream>>>(xbc, dtb, dab, Dvec, ybuf);
  // 8) gated rmsnorm, in-place on ybuf
  gated_kernel<<<T_TOK, 256, 0, stream>>>(ybuf, zx, gnorm_w, ybuf);
  // 9) h_k = y_gated @ out_proj_W^T -> d_out[24576..] as f32  (M=8192,N=1024,K=2048)
  gemm_bf16_kernel<true><<<(T_TOK/128)*(DM/128), 256, 0, stream>>>(ybuf, wout, hk, nullptr,
                                                                   T_TOK, DM, DI, DM);
  // 10) output = h_k @ dec_W^T + dec_b -> d_out[0..24576) as f32
  dec_kernel<<<T_TOK*3/4, 256, 0, stream>>>(hk, dec_W, dec_b, outp);
}

// Round 3
// 970.819 us; speedup vs baseline: 1.4704x; 1.4704x over previous
//
#include <hip/hip_runtime.h>
#include <stdint.h>

// ---- sizes ----
#define T_TOK 8192      // B*L = 4*2048
#define SEQL  2048
#define DM    1024
#define DI    2048
#define DSTATE 128
#define NH    32
#define HD    64
#define CONVD 2304      // DI + 2*DSTATE
#define DINP  4384      // 2*DI + 2*DSTATE + NH
#define LD_ZX 4480      // DINP padded to multiple of 128
#define SW    32        // scan LDS window (tokens)

typedef __attribute__((ext_vector_type(8))) __bf16 bfrag;
typedef __attribute__((ext_vector_type(8))) short s16x8;
typedef __attribute__((ext_vector_type(4))) float f32x4;

__device__ __forceinline__ float bf2f(unsigned short u){
  return __uint_as_float(((unsigned)u) << 16);
}
__device__ __forceinline__ unsigned short f2bf(float f){
  unsigned u = __float_as_uint(f);
  unsigned r = (u + 0x7FFFu + ((u >> 16) & 1u)) >> 16;   // RNE
  return (unsigned short)r;
}

__device__ __forceinline__ void gl_lds16(const unsigned short* g, unsigned short* l){
  __builtin_amdgcn_global_load_lds(
      (const __attribute__((address_space(1))) void*)g,
      (__attribute__((address_space(3))) void*)l,
      16, 0, 0);
}
__device__ __forceinline__ void gl_lds4(const float* g, float* l){
  __builtin_amdgcn_global_load_lds(
      (const __attribute__((address_space(1))) void*)g,
      (__attribute__((address_space(3))) void*)l,
      4, 0, 0);
}

// ---- weight f32 -> bf16 (with zero-pad tail for in_proj) ----
__global__ __launch_bounds__(256) void cvt_w_kernel(const float* __restrict__ src,
                                                    unsigned short* __restrict__ dst,
                                                    int n4, int srcn4){
  int i = blockIdx.x * 256 + threadIdx.x;
  if (i >= n4) return;
  ushort4 o;
  if (i < srcn4){
    float4 v = ((const float4*)src)[i];
    o.x = f2bf(v.x); o.y = f2bf(v.y); o.z = f2bf(v.z); o.w = f2bf(v.w);
  } else {
    o.x = o.y = o.z = o.w = 0;
  }
  *(ushort4*)(dst + (size_t)i * 4) = o;
}

// ---- rmsnorm(h_prev) | rmsnorm(emb_next) -> combined (T x 2048) bf16 ----
__global__ __launch_bounds__(256) void rmsnorm2_kernel(const float* __restrict__ a,
                                                       const float* __restrict__ b,
                                                       const float* __restrict__ w,
                                                       unsigned short* __restrict__ out){
  int t = blockIdx.x, tid = threadIdx.x;
  float4 va = *(const float4*)(a + (size_t)t * DM + tid * 4);
  float4 vb = *(const float4*)(b + (size_t)t * DM + tid * 4);
  float sa = va.x*va.x + va.y*va.y + va.z*va.z + va.w*va.w;
  float sb = vb.x*vb.x + vb.y*vb.y + vb.z*vb.z + vb.w*vb.w;
  #pragma unroll
  for (int o = 32; o; o >>= 1){ sa += __shfl_down(sa, o); sb += __shfl_down(sb, o); }
  __shared__ float reda[4], redb[4];
  int wv = tid >> 6, lane = tid & 63;
  if (!lane){ reda[wv] = sa; redb[wv] = sb; }
  __syncthreads();
  float ta = reda[0] + reda[1] + reda[2] + reda[3];
  float tb = redb[0] + redb[1] + redb[2] + redb[3];
  float ra = rsqrtf(ta * (1.f/1024.f) + 1e-6f);
  float rb = rsqrtf(tb * (1.f/1024.f) + 1e-6f);
  float4 vw = *(const float4*)(w + tid * 4);
  unsigned short* o0 = out + (size_t)t * DI + tid * 4;
  o0[0] = f2bf(va.x*ra*vw.x); o0[1] = f2bf(va.y*ra*vw.y);
  o0[2] = f2bf(va.z*ra*vw.z); o0[3] = f2bf(va.w*ra*vw.w);
  unsigned short* o1 = o0 + DM;
  o1[0] = f2bf(vb.x*rb*vw.x); o1[1] = f2bf(vb.y*rb*vw.y);
  o1[2] = f2bf(vb.z*rb*vw.z); o1[3] = f2bf(vb.w*rb*vw.w);
}

// ---- bf16 GEMM: C[M,ldc] = A[M,K] @ W[N,K]^T (+bias), 128x128 tile, BK=64 ----
template<bool F32OUT>
__global__ __launch_bounds__(256) void gemm_bf16_kernel(const unsigned short* __restrict__ A,
                                                        const unsigned short* __restrict__ W,
                                                        void* __restrict__ Cv,
                                                        const float* __restrict__ bias,
                                                        int M, int N, int K, int ldc){
  __shared__ unsigned short As[128 * 64];
  __shared__ unsigned short Bs[128 * 64];
  const int nN = N >> 7;
  const int bid = blockIdx.x;
  const int tm = bid / nN, tn = bid % nN;
  const int tid = threadIdx.x;
  const int wv = tid >> 6, lane = tid & 63;
  const int wm = wv >> 1, wn = wv & 1;
  const int rA = lane >> 3;            // 0..7
  const int cA = (lane & 7) << 3;      // 0,8,..,56
  const size_t arow0 = (size_t)(tm * 128) * K;
  const size_t brow0 = (size_t)(tn * 128) * K;

  f32x4 zero4 = {0.f, 0.f, 0.f, 0.f};
  f32x4 acc[4][4];
  #pragma unroll
  for (int i = 0; i < 4; ++i)
    #pragma unroll
    for (int j = 0; j < 4; ++j) acc[i][j] = zero4;

  const int nK = K >> 6;
  for (int kt = 0; kt < nK; ++kt){
    const int k0 = kt << 6;
    if (kt) __syncthreads();
    #pragma unroll
    for (int i = 0; i < 4; ++i){
      int base = (wv * 4 + i) * 8;      // 8 rows per issue
      gl_lds16(A + arow0 + (size_t)(base + rA) * K + k0 + cA, &As[base * 64]);
      gl_lds16(W + brow0 + (size_t)(base + rA) * K + k0 + cA, &Bs[base * 64]);
    }
    __syncthreads();   // compiler drains vmcnt before s_barrier
    #pragma unroll
    for (int kk = 0; kk < 2; ++kk){
      const int ko = kk * 32 + (lane >> 4) * 8;
      bfrag af[4], bfv[4];
      #pragma unroll
      for (int f = 0; f < 4; ++f){
        af[f]  = *reinterpret_cast<const bfrag*>(&As[(wm*64 + f*16 + (lane & 15)) * 64 + ko]);
        bfv[f] = *reinterpret_cast<const bfrag*>(&Bs[(wn*64 + f*16 + (lane & 15)) * 64 + ko]);
      }
      #pragma unroll
      for (int fm = 0; fm < 4; ++fm)
        #pragma unroll
        for (int fn = 0; fn < 4; ++fn)
          acc[fm][fn] = __builtin_amdgcn_mfma_f32_16x16x32_bf16(af[fm], bfv[fn], acc[fm][fn], 0, 0, 0);
    }
  }
  // epilogue: C/D layout col=lane&15, row=(lane>>4)*4+r
  const int r0 = (lane >> 4) * 4, ci = lane & 15;
  #pragma unroll
  for (int fm = 0; fm < 4; ++fm){
    #pragma unroll
    for (int fn = 0; fn < 4; ++fn){
      int col = tn*128 + wn*64 + fn*16 + ci;
      float bv = bias ? bias[col] : 0.f;
      #pragma unroll
      for (int r = 0; r < 4; ++r){
        int row = tm*128 + wm*64 + fm*16 + r0 + r;
        float val = acc[fm][fn][r] + bv;
        if (F32OUT) ((float*)Cv)[(size_t)row * ldc + col] = val;
        else        ((unsigned short*)Cv)[(size_t)row * ldc + col] = f2bf(val);
      }
    }
  }
}

// ---- causal depthwise conv(4) + bias + silu over xBC section of zx ----
__global__ __launch_bounds__(256) void conv_kernel(const unsigned short* __restrict__ zx,
                                                   const float* __restrict__ cw,
                                                   const float* __restrict__ cb,
                                                   unsigned short* __restrict__ xbc){
  int c = blockIdx.x * 256 + threadIdx.x;   // 0..2303
  int t = blockIdx.y;                        // 0..8191
  int l = t & (SEQL - 1);
  const unsigned short* base = zx + (size_t)t * LD_ZX + DI + c;
  float acc = cb[c];
  float w0 = cw[c*4+0], w1 = cw[c*4+1], w2 = cw[c*4+2], w3 = cw[c*4+3];
  if (l >= 3) acc += w0 * bf2f(*(base - 3 * LD_ZX));
  if (l >= 2) acc += w1 * bf2f(*(base - 2 * LD_ZX));
  if (l >= 1) acc += w2 * bf2f(*(base - 1 * LD_ZX));
  acc += w3 * bf2f(*base);
  float s = acc / (1.f + expf(-acc));        // silu
  xbc[(size_t)t * CONVD + c] = f2bf(s);
}

// ---- dt = softplus(dt_raw + bias); dA = exp(dt * -exp(A_log)) ----
__global__ __launch_bounds__(256) void dt_kernel(const unsigned short* __restrict__ zx,
                                                 const float* __restrict__ dtbias,
                                                 const float* __restrict__ alog,
                                                 float* __restrict__ dtb,
                                                 float* __restrict__ dab){
  int i = blockIdx.x * 256 + threadIdx.x;    // T*32
  int t = i >> 5, h = i & 31;
  float xr = bf2f(zx[(size_t)t * LD_ZX + 4352 + h]) + dtbias[h];
  float dt = (xr > 20.f) ? xr : log1pf(expf(xr));
  float A = -expf(alog[h]);
  dtb[i] = dt;
  dab[i] = expf(dt * A);
}

// ---- sequential SSM scan with double-buffered LDS token windows ----
// 256 blocks = (b, h, p-half); 256 thr = (pi 0..31) x (q 0..7); 16 states/thr.
__global__ __launch_bounds__(256) void scan_kernel(const unsigned short* __restrict__ xbc,
                                                   const float* __restrict__ dtb,
                                                   const float* __restrict__ dab,
                                                   const float* __restrict__ Dvec,
                                                   unsigned short* __restrict__ yout){
  __shared__ unsigned short Bb[2][SW * 128];
  __shared__ unsigned short Cb[2][SW * 128];
  __shared__ unsigned short Xb[2][SW * 32];
  __shared__ float DTb[2][64], DAb[2][64];   // padded to 64 (gl_lds4 writes 64 lanes)

  const int blk = blockIdx.x;
  const int b = blk >> 6, rem = blk & 63, h = rem >> 1, ph = rem & 1;
  const int tid = threadIdx.x;
  const int wv = tid >> 6, l = tid & 63;
  const int pi = tid >> 3;            // 0..31
  const int q  = tid & 7;             // 0..7
  const int p  = ph * 32 + pi;
  const int n0 = q * 16;
  const size_t tokBase = (size_t)b * SEQL;

  const unsigned short* gB = xbc + tokBase * CONVD + DI;             // B row start
  const unsigned short* gX = xbc + tokBase * CONVD + h * HD + ph*32; // this block's x slice
  const float* gdt = dtb + tokBase * NH + h;
  const float* gda = dab + tokBase * NH + h;

  auto stage = [&](int bi, int w){
    const int t0 = w * SW;
    // B and C windows: SW x 128 bf16 = 8 KB each = 8 chunks of 1KB; wave wv -> chunks wv*2, wv*2+1
    #pragma unroll
    for (int i = 0; i < 2; ++i){
      const int c = wv * 2 + i;
      const size_t row = (size_t)(t0 + c * 4 + (l >> 4)) * CONVD + ((l & 15) << 3);
      gl_lds16(gB + row,          &Bb[bi][c * 512]);
      gl_lds16(gB + DSTATE + row, &Cb[bi][c * 512]);
    }
    // x window: SW x 32 bf16 = 2 KB = 2 chunks; waves 2,3
    if (wv >= 2){
      const int j = wv - 2;
      const size_t row = (size_t)(t0 + j * 16 + (l >> 2)) * CONVD + ((l & 3) << 3);
      gl_lds16(gX + row, &Xb[bi][j * 512]);
    }
    // dt / dA: f32 scalars, one size-4 issue each (64 lanes, token clamped)
    int tc = t0 + l; if (tc > SEQL - 1) tc = SEQL - 1;
    if (wv == 0) gl_lds4(gdt + (size_t)tc * NH, &DTb[bi][0]);
    if (wv == 1) gl_lds4(gda + (size_t)tc * NH, &DAb[bi][0]);
  };

  float st[16];
  #pragma unroll
  for (int j = 0; j < 16; ++j) st[j] = 0.f;
  const float Dh = Dvec[h];

  stage(0, 0);
  __syncthreads();       // drains vmcnt(0) per wave, then joins

  for (int w = 0; w < SEQL / SW; ++w){
    const int cur = w & 1;
    if (w + 1 < SEQL / SW) stage(cur ^ 1, w + 1);   // issue next window, don't wait
    const int t0 = w * SW;

    // register-prefetch step 0 of this window
    s16x8 B0 = *(const s16x8*)&Bb[cur][n0];
    s16x8 B1 = *(const s16x8*)&Bb[cur][n0 + 8];
    s16x8 C0 = *(const s16x8*)&Cb[cur][n0];
    s16x8 C1 = *(const s16x8*)&Cb[cur][n0 + 8];
    float xv  = bf2f(Xb[cur][pi]);
    float dtv = DTb[cur][0], dAv = DAb[cur][0];

    #pragma unroll 2
    for (int s = 0; s < SW; ++s){
      s16x8 nB0, nB1, nC0, nC1; float nx = 0.f, ndt = 0.f, ndA = 0.f;
      const bool hasNext = (s + 1 < SW);
      if (hasNext){
        const int o = (s + 1) * 128 + n0;
        nB0 = *(const s16x8*)&Bb[cur][o];
        nB1 = *(const s16x8*)&Bb[cur][o + 8];
        nC0 = *(const s16x8*)&Cb[cur][o];
        nC1 = *(const s16x8*)&Cb[cur][o + 8];
        nx  = bf2f(Xb[cur][(s + 1) * 32 + pi]);
        ndt = DTb[cur][s + 1];
        ndA = DAb[cur][s + 1];
      }

      float c1 = dtv * xv;
      float accp = 0.f;
      #pragma unroll
      for (int j = 0; j < 8; ++j){
        float bj = bf2f((unsigned short)B0[j]);
        float cj = bf2f((unsigned short)C0[j]);
        st[j] = fmaf(st[j], dAv, c1 * bj);
        accp = fmaf(st[j], cj, accp);
      }
      #pragma unroll
      for (int j = 0; j < 8; ++j){
        float bj = bf2f((unsigned short)B1[j]);
        float cj = bf2f((unsigned short)C1[j]);
        st[8 + j] = fmaf(st[8 + j], dAv, c1 * bj);
        accp = fmaf(st[8 + j], cj, accp);
      }
      accp += __shfl_xor(accp, 1);
      accp += __shfl_xor(accp, 2);
      accp += __shfl_xor(accp, 4);
      if (q == 0)
        yout[(tokBase + t0 + s) * DI + h * HD + p] = f2bf(accp + Dh * xv);

      if (hasNext){
        B0 = nB0; B1 = nB1; C0 = nC0; C1 = nC1;
        xv = nx; dtv = ndt; dAv = ndA;
      }
    }
    __syncthreads();     // all waves done reading buf[cur]; next window's loads drained
  }
}

// ---- gated RMSNorm: out = gw * normalize(y * silu(z)); safe in-place on y ----
__global__ __launch_bounds__(256) void gated_kernel(const unsigned short* __restrict__ y,
                                                    const unsigned short* __restrict__ zx,
                                                    const float* __restrict__ gw,
                                                    unsigned short* __restrict__ out){
  int t = blockIdx.x, tid = threadIdx.x;
  s16x8 yv = *(const s16x8*)(y  + (size_t)t * DI    + tid * 8);
  s16x8 zv = *(const s16x8*)(zx + (size_t)t * LD_ZX + tid * 8);
  float g[8]; float ss = 0.f;
  #pragma unroll
  for (int j = 0; j < 8; ++j){
    float yf = bf2f((unsigned short)yv[j]);
    float zf = bf2f((unsigned short)zv[j]);
    float gi = yf * (zf / (1.f + expf(-zf)));
    g[j] = gi; ss += gi * gi;
  }
  #pragma unroll
  for (int o = 32; o; o >>= 1) ss += __shfl_down(ss, o);
  __shared__ float red[4];
  int wv = tid >> 6, lane = tid & 63;
  if (!lane) red[wv] = ss;
  __syncthreads();
  float tot = red[0] + red[1] + red[2] + red[3];
  float sc = rsqrtf(tot * (1.f/2048.f) + 1e-5f);
  unsigned short* o0 = out + (size_t)t * DI + tid * 8;
  #pragma unroll
  for (int j = 0; j < 8; ++j) o0[j] = f2bf(g[j] * sc * gw[tid * 8 + j]);
}

// ---- dec: output[t,v] = h_k[t,:] . dec_W[v,:] + dec_b[v]; one wave per dot ----
__global__ __launch_bounds__(256) void dec_kernel(const float* __restrict__ hk,
                                                  const float* __restrict__ dw,
                                                  const float* __restrict__ db,
                                                  float* __restrict__ out){
  int gwv = (blockIdx.x * 256 + threadIdx.x) >> 6;  // 0..24575
  int lane = threadIdx.x & 63;
  int t = gwv / 3, v = gwv - t * 3;
  const float* hr = hk + (size_t)t * DM + lane * 16;
  const float* wr = dw + v * DM + lane * 16;
  float acc = 0.f;
  #pragma unroll
  for (int j = 0; j < 16; ++j) acc = fmaf(hr[j], wr[j], acc);
  #pragma unroll
  for (int o = 32; o; o >>= 1) acc += __shfl_down(acc, o);
  if (!lane) out[t * 3 + v] = acc + db[v];
}

extern "C" void kernel_launch(void* const* d_in, const int* in_sizes, int n_in,
                              void* d_out, int out_size, void* d_ws, size_t ws_size,
                              hipStream_t stream){
  const float* h_prev    = (const float*)d_in[0];
  const float* emb_next  = (const float*)d_in[1];
  const float* norm_w    = (const float*)d_in[2];
  const float* proj_W    = (const float*)d_in[3];
  const float* proj_b    = (const float*)d_in[4];
  const float* in_proj_W = (const float*)d_in[5];
  const float* conv_w    = (const float*)d_in[6];
  const float* conv_b    = (const float*)d_in[7];
  const float* dt_bias   = (const float*)d_in[8];
  const float* A_log     = (const float*)d_in[9];
  const float* Dvec      = (const float*)d_in[10];
  const float* gnorm_w   = (const float*)d_in[11];
  const float* out_proj_W= (const float*)d_in[12];
  const float* dec_W     = (const float*)d_in[13];
  const float* dec_b     = (const float*)d_in[14];

  char* ws = (char*)d_ws;
  size_t off = 0;
  auto take = [&](size_t bytes){ char* p = ws + off; off += (bytes + 255) & ~(size_t)255; return p; };
  unsigned short* wproj = (unsigned short*)take((size_t)DM * DI * 2);
  unsigned short* winp  = (unsigned short*)take((size_t)LD_ZX * DM * 2);
  unsigned short* wout  = (unsigned short*)take((size_t)DM * DI * 2);
  unsigned short* zx    = (unsigned short*)take((size_t)T_TOK * LD_ZX * 2);
  float*          dtb   = (float*)take((size_t)T_TOK * NH * 4);
  float*          dab   = (float*)take((size_t)T_TOK * NH * 4);
  // region A: combined(32MB) + hprime(16MB); later overlaid by xbc(36MB)
  char* regionA = take((size_t)T_TOK * DI * 2 + (size_t)T_TOK * DM * 2);
  unsigned short* combined = (unsigned short*)regionA;
  unsigned short* hprime   = (unsigned short*)(regionA + (size_t)T_TOK * DI * 2);
  unsigned short* xbc      = (unsigned short*)regionA;           // overlays dead combined+hprime
  unsigned short* ybuf     = (unsigned short*)take((size_t)T_TOK * DI * 2);  // gated in-place

  float* outp = (float*)d_out;                   // [T*3] output, then [T*1024] h_k (f32)
  float* hk   = outp + (size_t)T_TOK * 3;

  // 1) weights -> bf16 (in_proj padded 4384->4480 rows with zeros)
  cvt_w_kernel<<<2048, 256, 0, stream>>>(proj_W, wproj, DM*DI/4, DM*DI/4);
  cvt_w_kernel<<<4480, 256, 0, stream>>>(in_proj_W, winp, LD_ZX*DM/4, DINP*DM/4);
  cvt_w_kernel<<<2048, 256, 0, stream>>>(out_proj_W, wout, DM*DI/4, DM*DI/4);

  // 2) dual rmsnorm -> combined (T x 2048)
  rmsnorm2_kernel<<<T_TOK, 256, 0, stream>>>(h_prev, emb_next, norm_w, combined);

  // 3) h_prime = combined @ proj_W^T + proj_b   (M=8192,N=1024,K=2048)
  gemm_bf16_kernel<false><<<(T_TOK/128)*(DM/128), 256, 0, stream>>>(combined, wproj, hprime, proj_b,
                                                                    T_TOK, DM, DI, DM);
  // 4) zxbcdt = h_prime @ in_proj_W^T           (M=8192,N=4480,K=1024)
  gemm_bf16_kernel<false><<<(T_TOK/128)*(LD_ZX/128), 256, 0, stream>>>(hprime, winp, zx, nullptr,
                                                                       T_TOK, LD_ZX, DM, LD_ZX);
  // 5) conv + silu on xBC  (xbc overlays combined/hprime which are now dead)
  conv_kernel<<<dim3(CONVD/256, T_TOK), 256, 0, stream>>>(zx, conv_w, conv_b, xbc);
  // 6) dt / dA
  dt_kernel<<<T_TOK*NH/256, 256, 0, stream>>>(zx, dt_bias, A_log, dtb, dab);
  // 7) SSM scan -> y (+ D*x), LDS-windowed
  scan_kernel<<<256, 256, 0, stream>>>(xbc, dtb, dab, Dvec, ybuf);
  // 8) gated rmsnorm, in-place on ybuf
  gated_kernel<<<T_TOK, 256, 0, stream>>>(ybuf, zx, gnorm_w, ybuf);
  // 9) h_k = y_gated @ out_proj_W^T -> d_out[24576..] as f32  (M=8192,N=1024,K=2048)
  gemm_bf16_kernel<true><<<(T_TOK/128)*(DM/128), 256, 0, stream>>>(ybuf, wout, hk, nullptr,
                                                                   T_TOK, DM, DI, DM);
  // 10) output = h_k @ dec_W^T + dec_b -> d_out[0..24576) as f32
  dec_kernel<<<T_TOK*3/4, 256, 0, stream>>>(hk, dec_W, dec_b, outp);
}

// Round 4
// 938.072 us; speedup vs baseline: 1.5218x; 1.0349x over previous
//
#include <hip/hip_runtime.h>
#include <stdint.h>

// ---- sizes ----
#define T_TOK 8192      // B*L = 4*2048
#define SEQL  2048
#define DM    1024
#define DI    2048
#define DSTATE 128
#define NH    32
#define HD    64
#define CONVD 2304      // DI + 2*DSTATE
#define DINP  4384      // 2*DI + 2*DSTATE + NH
#define LD_ZX 4480      // DINP padded to multiple of 128
#define SW    32        // scan LDS window (tokens)

typedef __attribute__((ext_vector_type(8))) __bf16 bfrag;
typedef __attribute__((ext_vector_type(8))) short s16x8;
typedef __attribute__((ext_vector_type(4))) float f32x4;

__device__ __forceinline__ float bf2f(unsigned short u){
  return __uint_as_float(((unsigned)u) << 16);
}
__device__ __forceinline__ unsigned short f2bf(float f){
  unsigned u = __float_as_uint(f);
  unsigned r = (u + 0x7FFFu + ((u >> 16) & 1u)) >> 16;   // RNE
  return (unsigned short)r;
}

__device__ __forceinline__ void gl_lds16(const unsigned short* g, unsigned short* l){
  __builtin_amdgcn_global_load_lds(
      (const __attribute__((address_space(1))) void*)g,
      (__attribute__((address_space(3))) void*)l,
      16, 0, 0);
}
__device__ __forceinline__ void gl_lds4(const float* g, float* l){
  __builtin_amdgcn_global_load_lds(
      (const __attribute__((address_space(1))) void*)g,
      (__attribute__((address_space(3))) void*)l,
      4, 0, 0);
}

// ---- weight f32 -> bf16 (with zero-pad tail for in_proj) ----
__global__ __launch_bounds__(256) void cvt_w_kernel(const float* __restrict__ src,
                                                    unsigned short* __restrict__ dst,
                                                    int n4, int srcn4){
  int i = blockIdx.x * 256 + threadIdx.x;
  if (i >= n4) return;
  ushort4 o;
  if (i < srcn4){
    float4 v = ((const float4*)src)[i];
    o.x = f2bf(v.x); o.y = f2bf(v.y); o.z = f2bf(v.z); o.w = f2bf(v.w);
  } else {
    o.x = o.y = o.z = o.w = 0;
  }
  *(ushort4*)(dst + (size_t)i * 4) = o;
}

// ---- rmsnorm(h_prev) | rmsnorm(emb_next) -> combined (T x 2048) bf16 ----
__global__ __launch_bounds__(256) void rmsnorm2_kernel(const float* __restrict__ a,
                                                       const float* __restrict__ b,
                                                       const float* __restrict__ w,
                                                       unsigned short* __restrict__ out){
  int t = blockIdx.x, tid = threadIdx.x;
  float4 va = *(const float4*)(a + (size_t)t * DM + tid * 4);
  float4 vb = *(const float4*)(b + (size_t)t * DM + tid * 4);
  float sa = va.x*va.x + va.y*va.y + va.z*va.z + va.w*va.w;
  float sb = vb.x*vb.x + vb.y*vb.y + vb.z*vb.z + vb.w*vb.w;
  #pragma unroll
  for (int o = 32; o; o >>= 1){ sa += __shfl_down(sa, o); sb += __shfl_down(sb, o); }
  __shared__ float reda[4], redb[4];
  int wv = tid >> 6, lane = tid & 63;
  if (!lane){ reda[wv] = sa; redb[wv] = sb; }
  __syncthreads();
  float ta = reda[0] + reda[1] + reda[2] + reda[3];
  float tb = redb[0] + redb[1] + redb[2] + redb[3];
  float ra = rsqrtf(ta * (1.f/1024.f) + 1e-6f);
  float rb = rsqrtf(tb * (1.f/1024.f) + 1e-6f);
  float4 vw = *(const float4*)(w + tid * 4);
  unsigned short* o0 = out + (size_t)t * DI + tid * 4;
  o0[0] = f2bf(va.x*ra*vw.x); o0[1] = f2bf(va.y*ra*vw.y);
  o0[2] = f2bf(va.z*ra*vw.z); o0[3] = f2bf(va.w*ra*vw.w);
  unsigned short* o1 = o0 + DM;
  o1[0] = f2bf(vb.x*rb*vw.x); o1[1] = f2bf(vb.y*rb*vw.y);
  o1[2] = f2bf(vb.z*rb*vw.z); o1[3] = f2bf(vb.w*rb*vw.w);
}

// ---- bf16 GEMM: C[M,ldc] = A[M,K] @ W[N,K]^T (+bias), 128x128 tile, BK=64 ----
template<bool F32OUT>
__global__ __launch_bounds__(256) void gemm_bf16_kernel(const unsigned short* __restrict__ A,
                                                        const unsigned short* __restrict__ W,
                                                        void* __restrict__ Cv,
                                                        const float* __restrict__ bias,
                                                        int M, int N, int K, int ldc){
  __shared__ unsigned short As[128 * 64];
  __shared__ unsigned short Bs[128 * 64];
  const int nN = N >> 7;
  const int bid = blockIdx.x;
  const int tm = bid / nN, tn = bid % nN;
  const int tid = threadIdx.x;
  const int wv = tid >> 6, lane = tid & 63;
  const int wm = wv >> 1, wn = wv & 1;
  const int rA = lane >> 3;            // 0..7
  const int cA = (lane & 7) << 3;      // 0,8,..,56
  const size_t arow0 = (size_t)(tm * 128) * K;
  const size_t brow0 = (size_t)(tn * 128) * K;

  f32x4 zero4 = {0.f, 0.f, 0.f, 0.f};
  f32x4 acc[4][4];
  #pragma unroll
  for (int i = 0; i < 4; ++i)
    #pragma unroll
    for (int j = 0; j < 4; ++j) acc[i][j] = zero4;

  const int nK = K >> 6;
  for (int kt = 0; kt < nK; ++kt){
    const int k0 = kt << 6;
    if (kt) __syncthreads();
    #pragma unroll
    for (int i = 0; i < 4; ++i){
      int base = (wv * 4 + i) * 8;      // 8 rows per issue
      gl_lds16(A + arow0 + (size_t)(base + rA) * K + k0 + cA, &As[base * 64]);
      gl_lds16(W + brow0 + (size_t)(base + rA) * K + k0 + cA, &Bs[base * 64]);
    }
    __syncthreads();   // compiler drains vmcnt before s_barrier
    #pragma unroll
    for (int kk = 0; kk < 2; ++kk){
      const int ko = kk * 32 + (lane >> 4) * 8;
      bfrag af[4], bfv[4];
      #pragma unroll
      for (int f = 0; f < 4; ++f){
        af[f]  = *reinterpret_cast<const bfrag*>(&As[(wm*64 + f*16 + (lane & 15)) * 64 + ko]);
        bfv[f] = *reinterpret_cast<const bfrag*>(&Bs[(wn*64 + f*16 + (lane & 15)) * 64 + ko]);
      }
      #pragma unroll
      for (int fm = 0; fm < 4; ++fm)
        #pragma unroll
        for (int fn = 0; fn < 4; ++fn)
          acc[fm][fn] = __builtin_amdgcn_mfma_f32_16x16x32_bf16(af[fm], bfv[fn], acc[fm][fn], 0, 0, 0);
    }
  }
  // epilogue: C/D layout col=lane&15, row=(lane>>4)*4+r
  const int r0 = (lane >> 4) * 4, ci = lane & 15;
  #pragma unroll
  for (int fm = 0; fm < 4; ++fm){
    #pragma unroll
    for (int fn = 0; fn < 4; ++fn){
      int col = tn*128 + wn*64 + fn*16 + ci;
      float bv = bias ? bias[col] : 0.f;
      #pragma unroll
      for (int r = 0; r < 4; ++r){
        int row = tm*128 + wm*64 + fm*16 + r0 + r;
        float val = acc[fm][fn][r] + bv;
        if (F32OUT) ((float*)Cv)[(size_t)row * ldc + col] = val;
        else        ((unsigned short*)Cv)[(size_t)row * ldc + col] = f2bf(val);
      }
    }
  }
}

// ---- causal depthwise conv(4) + bias + silu over xBC section of zx ----
__global__ __launch_bounds__(256) void conv_kernel(const unsigned short* __restrict__ zx,
                                                   const float* __restrict__ cw,
                                                   const float* __restrict__ cb,
                                                   unsigned short* __restrict__ xbc){
  int c = blockIdx.x * 256 + threadIdx.x;   // 0..2303
  int t = blockIdx.y;                        // 0..8191
  int l = t & (SEQL - 1);
  const unsigned short* base = zx + (size_t)t * LD_ZX + DI + c;
  float acc = cb[c];
  float w0 = cw[c*4+0], w1 = cw[c*4+1], w2 = cw[c*4+2], w3 = cw[c*4+3];
  if (l >= 3) acc += w0 * bf2f(*(base - 3 * LD_ZX));
  if (l >= 2) acc += w1 * bf2f(*(base - 2 * LD_ZX));
  if (l >= 1) acc += w2 * bf2f(*(base - 1 * LD_ZX));
  acc += w3 * bf2f(*base);
  float s = acc / (1.f + expf(-acc));        // silu
  xbc[(size_t)t * CONVD + c] = f2bf(s);
}

// ---- dt = softplus(dt_raw + bias); dA = exp(dt * -exp(A_log)) ----
__global__ __launch_bounds__(256) void dt_kernel(const unsigned short* __restrict__ zx,
                                                 const float* __restrict__ dtbias,
                                                 const float* __restrict__ alog,
                                                 float* __restrict__ dtb,
                                                 float* __restrict__ dab){
  int i = blockIdx.x * 256 + threadIdx.x;    // T*32
  int t = i >> 5, h = i & 31;
  float xr = bf2f(zx[(size_t)t * LD_ZX + 4352 + h]) + dtbias[h];
  float dt = (xr > 20.f) ? xr : log1pf(expf(xr));
  float A = -expf(alog[h]);
  dtb[i] = dt;
  dab[i] = expf(dt * A);
}

// ---- sequential SSM scan, LDS-windowed, p split 4-way for TLP ----
// 512 blocks = (b, h, pb); 256 thr = (pj 0..15) x (q 0..15); 8 states/thr.
__global__ __launch_bounds__(256) void scan_kernel(const unsigned short* __restrict__ xbc,
                                                   const float* __restrict__ dtb,
                                                   const float* __restrict__ dab,
                                                   const float* __restrict__ Dvec,
                                                   unsigned short* __restrict__ yout){
  __shared__ unsigned short Bb[2][SW * 128];
  __shared__ unsigned short Cb[2][SW * 128];
  __shared__ unsigned short Xb[2][SW * 16];
  __shared__ float DTb[2][64], DAb[2][64];   // 64-padded (gl_lds4 writes 64 lanes)

  const int blk = blockIdx.x;                // 4b x 32h x 4pb
  const int b = blk >> 7, h = (blk >> 2) & 31, pb = blk & 3;
  const int p0 = pb * 16;
  const int tid = threadIdx.x;
  const int wv = tid >> 6, l = tid & 63;
  const int pj = tid >> 4;            // 0..15
  const int q  = tid & 15;            // 0..15
  const int n0 = q * 8;
  const size_t tokBase = (size_t)b * SEQL;

  const unsigned short* gB = xbc + tokBase * CONVD + DI;
  const unsigned short* gX = xbc + tokBase * CONVD + h * HD + p0;
  const float* gdt = dtb + tokBase * NH + h;
  const float* gda = dab + tokBase * NH + h;

  auto stage = [&](int bi, int w){
    const int t0 = w * SW;
    // B, C windows: SW x 128 bf16 = 8 KB each = 8 chunks of 1 KB; wave wv -> 2 chunks
    #pragma unroll
    for (int i = 0; i < 2; ++i){
      const int c = wv * 2 + i;
      const size_t row = (size_t)(t0 + c * 4 + (l >> 4)) * CONVD + ((l & 15) << 3);
      gl_lds16(gB + row,          &Bb[bi][c * 512]);
      gl_lds16(gB + DSTATE + row, &Cb[bi][c * 512]);
    }
    // x window: SW tokens x 16 p = 1 KB; lane l -> token t0+(l>>1), p-half l&1
    if (wv == 0){
      const size_t xo = (size_t)(t0 + (l >> 1)) * CONVD + ((l & 1) << 3);
      gl_lds16(gX + xo, &Xb[bi][0]);
    }
    // dt / dA scalars (lanes beyond window clamp; surplus lanes write unused slots)
    int tc = t0 + l; if (tc > SEQL - 1) tc = SEQL - 1;
    if (wv == 1) gl_lds4(gdt + (size_t)tc * NH, &DTb[bi][0]);
    if (wv == 2) gl_lds4(gda + (size_t)tc * NH, &DAb[bi][0]);
  };

  float st[8];
  #pragma unroll
  for (int j = 0; j < 8; ++j) st[j] = 0.f;
  const float Dh = Dvec[h];

  stage(0, 0);
  __syncthreads();

  for (int w = 0; w < SEQL / SW; ++w){
    const int cur = w & 1;
    if (w + 1 < SEQL / SW) stage(cur ^ 1, w + 1);   // issue next window, don't wait
    const int t0 = w * SW;

    s16x8 B0 = *(const s16x8*)&Bb[cur][n0];
    s16x8 C0 = *(const s16x8*)&Cb[cur][n0];
    float xv  = bf2f(Xb[cur][pj]);
    float dtv = DTb[cur][0], dAv = DAb[cur][0];

    #pragma unroll 2
    for (int s = 0; s < SW; ++s){
      s16x8 nB0, nC0; float nx = 0.f, ndt = 0.f, ndA = 0.f;
      const bool hasNext = (s + 1 < SW);
      if (hasNext){
        const int o = (s + 1) * 128 + n0;
        nB0 = *(const s16x8*)&Bb[cur][o];
        nC0 = *(const s16x8*)&Cb[cur][o];
        nx  = bf2f(Xb[cur][(s + 1) * 16 + pj]);
        ndt = DTb[cur][s + 1];
        ndA = DAb[cur][s + 1];
      }

      float c1 = dtv * xv;
      float accp = 0.f;
      #pragma unroll
      for (int j = 0; j < 8; ++j){
        float bj = bf2f((unsigned short)B0[j]);
        float cj = bf2f((unsigned short)C0[j]);
        st[j] = fmaf(st[j], dAv, c1 * bj);
        accp = fmaf(st[j], cj, accp);
      }
      accp += __shfl_xor(accp, 1);
      accp += __shfl_xor(accp, 2);
      accp += __shfl_xor(accp, 4);
      accp += __shfl_xor(accp, 8);
      if (q == 0)
        yout[(tokBase + t0 + s) * DI + h * HD + p0 + pj] = f2bf(accp + Dh * xv);

      if (hasNext){
        B0 = nB0; C0 = nC0;
        xv = nx; dtv = ndt; dAv = ndA;
      }
    }
    __syncthreads();     // all waves done with buf[cur]; next window drained
  }
}

// ---- gated RMSNorm: out = gw * normalize(y * silu(z)); safe in-place on y ----
__global__ __launch_bounds__(256) void gated_kernel(const unsigned short* __restrict__ y,
                                                    const unsigned short* __restrict__ zx,
                                                    const float* __restrict__ gw,
                                                    unsigned short* __restrict__ out){
  int t = blockIdx.x, tid = threadIdx.x;
  s16x8 yv = *(const s16x8*)(y  + (size_t)t * DI    + tid * 8);
  s16x8 zv = *(const s16x8*)(zx + (size_t)t * LD_ZX + tid * 8);
  float g[8]; float ss = 0.f;
  #pragma unroll
  for (int j = 0; j < 8; ++j){
    float yf = bf2f((unsigned short)yv[j]);
    float zf = bf2f((unsigned short)zv[j]);
    float gi = yf * (zf / (1.f + expf(-zf)));
    g[j] = gi; ss += gi * gi;
  }
  #pragma unroll
  for (int o = 32; o; o >>= 1) ss += __shfl_down(ss, o);
  __shared__ float red[4];
  int wv = tid >> 6, lane = tid & 63;
  if (!lane) red[wv] = ss;
  __syncthreads();
  float tot = red[0] + red[1] + red[2] + red[3];
  float sc = rsqrtf(tot * (1.f/2048.f) + 1e-5f);
  unsigned short* o0 = out + (size_t)t * DI + tid * 8;
  #pragma unroll
  for (int j = 0; j < 8; ++j) o0[j] = f2bf(g[j] * sc * gw[tid * 8 + j]);
}

// ---- dec: output[t,v] = h_k[t,:] . dec_W[v,:] + dec_b[v]; one wave per dot ----
__global__ __launch_bounds__(256) void dec_kernel(const float* __restrict__ hk,
                                                  const float* __restrict__ dw,
                                                  const float* __restrict__ db,
                                                  float* __restrict__ out){
  int gwv = (blockIdx.x * 256 + threadIdx.x) >> 6;  // 0..24575
  int lane = threadIdx.x & 63;
  int t = gwv / 3, v = gwv - t * 3;
  const float* hr = hk + (size_t)t * DM + lane * 16;
  const float* wr = dw + v * DM + lane * 16;
  float acc = 0.f;
  #pragma unroll
  for (int j = 0; j < 16; ++j) acc = fmaf(hr[j], wr[j], acc);
  #pragma unroll
  for (int o = 32; o; o >>= 1) acc += __shfl_down(acc, o);
  if (!lane) out[t * 3 + v] = acc + db[v];
}

extern "C" void kernel_launch(void* const* d_in, const int* in_sizes, int n_in,
                              void* d_out, int out_size, void* d_ws, size_t ws_size,
                              hipStream_t stream){
  const float* h_prev    = (const float*)d_in[0];
  const float* emb_next  = (const float*)d_in[1];
  const float* norm_w    = (const float*)d_in[2];
  const float* proj_W    = (const float*)d_in[3];
  const float* proj_b    = (const float*)d_in[4];
  const float* in_proj_W = (const float*)d_in[5];
  const float* conv_w    = (const float*)d_in[6];
  const float* conv_b    = (const float*)d_in[7];
  const float* dt_bias   = (const float*)d_in[8];
  const float* A_log     = (const float*)d_in[9];
  const float* Dvec      = (const float*)d_in[10];
  const float* gnorm_w   = (const float*)d_in[11];
  const float* out_proj_W= (const float*)d_in[12];
  const float* dec_W     = (const float*)d_in[13];
  const float* dec_b     = (const float*)d_in[14];

  char* ws = (char*)d_ws;
  size_t off = 0;
  auto take = [&](size_t bytes){ char* p = ws + off; off += (bytes + 255) & ~(size_t)255; return p; };
  unsigned short* wproj = (unsigned short*)take((size_t)DM * DI * 2);
  unsigned short* winp  = (unsigned short*)take((size_t)LD_ZX * DM * 2);
  unsigned short* wout  = (unsigned short*)take((size_t)DM * DI * 2);
  unsigned short* zx    = (unsigned short*)take((size_t)T_TOK * LD_ZX * 2);
  float*          dtb   = (float*)take((size_t)T_TOK * NH * 4);
  float*          dab   = (float*)take((size_t)T_TOK * NH * 4);
  // region A: combined(32MB) + hprime(16MB); later overlaid by xbc(36MB)
  char* regionA = take((size_t)T_TOK * DI * 2 + (size_t)T_TOK * DM * 2);
  unsigned short* combined = (unsigned short*)regionA;
  unsigned short* hprime   = (unsigned short*)(regionA + (size_t)T_TOK * DI * 2);
  unsigned short* xbc      = (unsigned short*)regionA;           // overlays dead combined+hprime
  unsigned short* ybuf     = (unsigned short*)take((size_t)T_TOK * DI * 2);  // gated in-place

  float* outp = (float*)d_out;                   // [T*3] output, then [T*1024] h_k (f32)
  float* hk   = outp + (size_t)T_TOK * 3;

  // 1) weights -> bf16 (in_proj padded 4384->4480 rows with zeros)
  cvt_w_kernel<<<2048, 256, 0, stream>>>(proj_W, wproj, DM*DI/4, DM*DI/4);
  cvt_w_kernel<<<4480, 256, 0, stream>>>(in_proj_W, winp, LD_ZX*DM/4, DINP*DM/4);
  cvt_w_kernel<<<2048, 256, 0, stream>>>(out_proj_W, wout, DM*DI/4, DM*DI/4);

  // 2) dual rmsnorm -> combined (T x 2048)
  rmsnorm2_kernel<<<T_TOK, 256, 0, stream>>>(h_prev, emb_next, norm_w, combined);

  // 3) h_prime = combined @ proj_W^T + proj_b   (M=8192,N=1024,K=2048)
  gemm_bf16_kernel<false><<<(T_TOK/128)*(DM/128), 256, 0, stream>>>(combined, wproj, hprime, proj_b,
                                                                    T_TOK, DM, DI, DM);
  // 4) zxbcdt = h_prime @ in_proj_W^T           (M=8192,N=4480,K=1024)
  gemm_bf16_kernel<false><<<(T_TOK/128)*(LD_ZX/128), 256, 0, stream>>>(hprime, winp, zx, nullptr,
                                                                       T_TOK, LD_ZX, DM, LD_ZX);
  // 5) conv + silu on xBC  (xbc overlays combined/hprime which are now dead)
  conv_kernel<<<dim3(CONVD/256, T_TOK), 256, 0, stream>>>(zx, conv_w, conv_b, xbc);
  // 6) dt / dA
  dt_kernel<<<T_TOK*NH/256, 256, 0, stream>>>(zx, dt_bias, A_log, dtb, dab);
  // 7) SSM scan -> y (+ D*x), LDS-windowed, 512 blocks
  scan_kernel<<<512, 256, 0, stream>>>(xbc, dtb, dab, Dvec, ybuf);
  // 8) gated rmsnorm, in-place on ybuf
  gated_kernel<<<T_TOK, 256, 0, stream>>>(ybuf, zx, gnorm_w, ybuf);
  // 9) h_k = y_gated @ out_proj_W^T -> d_out[24576..] as f32  (M=8192,N=1024,K=2048)
  gemm_bf16_kernel<true><<<(T_TOK/128)*(DM/128), 256, 0, stream>>>(ybuf, wout, hk, nullptr,
                                                                   T_TOK, DM, DI, DM);
  // 10) output = h_k @ dec_W^T + dec_b -> d_out[0..24576) as f32
  dec_kernel<<<T_TOK*3/4, 256, 0, stream>>>(hk, dec_W, dec_b, outp);
}

// Round 5
// 935.975 us; speedup vs baseline: 1.5252x; 1.0022x over previous
//
#include <hip/hip_runtime.h>
#include <stdint.h>

// ---- sizes ----
#define T_TOK 8192      // B*L = 4*2048
#define SEQL  2048
#define DM    1024
#define DI    2048
#define DSTATE 128
#define NH    32
#define HD    64
#define CONVD 2304      // DI + 2*DSTATE
#define DINP  4384      // 2*DI + 2*DSTATE + NH
#define LD_ZX 4480      // DINP padded to multiple of 128
#define SW    32        // scan LDS window (tokens)

typedef __attribute__((ext_vector_type(8))) __bf16 bfrag;
typedef __attribute__((ext_vector_type(8))) short s16x8;
typedef __attribute__((ext_vector_type(4))) float f32x4;

__device__ __forceinline__ float bf2f(unsigned short u){
  return __uint_as_float(((unsigned)u) << 16);
}
__device__ __forceinline__ unsigned short f2bf(float f){
  unsigned u = __float_as_uint(f);
  unsigned r = (u + 0x7FFFu + ((u >> 16) & 1u)) >> 16;   // RNE
  return (unsigned short)r;
}

__device__ __forceinline__ void gl_lds16(const unsigned short* g, unsigned short* l){
  __builtin_amdgcn_global_load_lds(
      (const __attribute__((address_space(1))) void*)g,
      (__attribute__((address_space(3))) void*)l,
      16, 0, 0);
}
__device__ __forceinline__ void gl_lds4(const float* g, float* l){
  __builtin_amdgcn_global_load_lds(
      (const __attribute__((address_space(1))) void*)g,
      (__attribute__((address_space(3))) void*)l,
      4, 0, 0);
}

// ---- weight f32 -> bf16 (with zero-pad tail for in_proj) ----
__global__ __launch_bounds__(256) void cvt_w_kernel(const float* __restrict__ src,
                                                    unsigned short* __restrict__ dst,
                                                    int n4, int srcn4){
  int i = blockIdx.x * 256 + threadIdx.x;
  if (i >= n4) return;
  ushort4 o;
  if (i < srcn4){
    float4 v = ((const float4*)src)[i];
    o.x = f2bf(v.x); o.y = f2bf(v.y); o.z = f2bf(v.z); o.w = f2bf(v.w);
  } else {
    o.x = o.y = o.z = o.w = 0;
  }
  *(ushort4*)(dst + (size_t)i * 4) = o;
}

// ---- rmsnorm(h_prev) | rmsnorm(emb_next) -> combined (T x 2048) bf16 ----
__global__ __launch_bounds__(256) void rmsnorm2_kernel(const float* __restrict__ a,
                                                       const float* __restrict__ b,
                                                       const float* __restrict__ w,
                                                       unsigned short* __restrict__ out){
  int t = blockIdx.x, tid = threadIdx.x;
  float4 va = *(const float4*)(a + (size_t)t * DM + tid * 4);
  float4 vb = *(const float4*)(b + (size_t)t * DM + tid * 4);
  float sa = va.x*va.x + va.y*va.y + va.z*va.z + va.w*va.w;
  float sb = vb.x*vb.x + vb.y*vb.y + vb.z*vb.z + vb.w*vb.w;
  #pragma unroll
  for (int o = 32; o; o >>= 1){ sa += __shfl_down(sa, o); sb += __shfl_down(sb, o); }
  __shared__ float reda[4], redb[4];
  int wv = tid >> 6, lane = tid & 63;
  if (!lane){ reda[wv] = sa; redb[wv] = sb; }
  __syncthreads();
  float ta = reda[0] + reda[1] + reda[2] + reda[3];
  float tb = redb[0] + redb[1] + redb[2] + redb[3];
  float ra = rsqrtf(ta * (1.f/1024.f) + 1e-6f);
  float rb = rsqrtf(tb * (1.f/1024.f) + 1e-6f);
  float4 vw = *(const float4*)(w + tid * 4);
  unsigned short* o0 = out + (size_t)t * DI + tid * 4;
  o0[0] = f2bf(va.x*ra*vw.x); o0[1] = f2bf(va.y*ra*vw.y);
  o0[2] = f2bf(va.z*ra*vw.z); o0[3] = f2bf(va.w*ra*vw.w);
  unsigned short* o1 = o0 + DM;
  o1[0] = f2bf(vb.x*rb*vw.x); o1[1] = f2bf(vb.y*rb*vw.y);
  o1[2] = f2bf(vb.z*rb*vw.z); o1[3] = f2bf(vb.w*rb*vw.w);
}

// ---- bf16 GEMM: C[M,ldc] = A[M,K] @ W[N,K]^T (+bias), 128x128 tile, BK=64 ----
template<bool F32OUT>
__global__ __launch_bounds__(256) void gemm_bf16_kernel(const unsigned short* __restrict__ A,
                                                        const unsigned short* __restrict__ W,
                                                        void* __restrict__ Cv,
                                                        const float* __restrict__ bias,
                                                        int M, int N, int K, int ldc){
  __shared__ unsigned short As[128 * 64];
  __shared__ unsigned short Bs[128 * 64];
  const int nN = N >> 7;
  const int bid = blockIdx.x;
  const int tm = bid / nN, tn = bid % nN;
  const int tid = threadIdx.x;
  const int wv = tid >> 6, lane = tid & 63;
  const int wm = wv >> 1, wn = wv & 1;
  const int rA = lane >> 3;            // 0..7
  const int cA = (lane & 7) << 3;      // 0,8,..,56
  const size_t arow0 = (size_t)(tm * 128) * K;
  const size_t brow0 = (size_t)(tn * 128) * K;

  f32x4 zero4 = {0.f, 0.f, 0.f, 0.f};
  f32x4 acc[4][4];
  #pragma unroll
  for (int i = 0; i < 4; ++i)
    #pragma unroll
    for (int j = 0; j < 4; ++j) acc[i][j] = zero4;

  const int nK = K >> 6;
  for (int kt = 0; kt < nK; ++kt){
    const int k0 = kt << 6;
    if (kt) __syncthreads();
    #pragma unroll
    for (int i = 0; i < 4; ++i){
      int base = (wv * 4 + i) * 8;      // 8 rows per issue
      gl_lds16(A + arow0 + (size_t)(base + rA) * K + k0 + cA, &As[base * 64]);
      gl_lds16(W + brow0 + (size_t)(base + rA) * K + k0 + cA, &Bs[base * 64]);
    }
    __syncthreads();   // compiler drains vmcnt before s_barrier
    #pragma unroll
    for (int kk = 0; kk < 2; ++kk){
      const int ko = kk * 32 + (lane >> 4) * 8;
      bfrag af[4], bfv[4];
      #pragma unroll
      for (int f = 0; f < 4; ++f){
        af[f]  = *reinterpret_cast<const bfrag*>(&As[(wm*64 + f*16 + (lane & 15)) * 64 + ko]);
        bfv[f] = *reinterpret_cast<const bfrag*>(&Bs[(wn*64 + f*16 + (lane & 15)) * 64 + ko]);
      }
      #pragma unroll
      for (int fm = 0; fm < 4; ++fm)
        #pragma unroll
        for (int fn = 0; fn < 4; ++fn)
          acc[fm][fn] = __builtin_amdgcn_mfma_f32_16x16x32_bf16(af[fm], bfv[fn], acc[fm][fn], 0, 0, 0);
    }
  }
  // epilogue: C/D layout col=lane&15, row=(lane>>4)*4+r
  const int r0 = (lane >> 4) * 4, ci = lane & 15;
  #pragma unroll
  for (int fm = 0; fm < 4; ++fm){
    #pragma unroll
    for (int fn = 0; fn < 4; ++fn){
      int col = tn*128 + wn*64 + fn*16 + ci;
      float bv = bias ? bias[col] : 0.f;
      #pragma unroll
      for (int r = 0; r < 4; ++r){
        int row = tm*128 + wm*64 + fm*16 + r0 + r;
        float val = acc[fm][fn][r] + bv;
        if (F32OUT) ((float*)Cv)[(size_t)row * ldc + col] = val;
        else        ((unsigned short*)Cv)[(size_t)row * ldc + col] = f2bf(val);
      }
    }
  }
}

// ---- causal depthwise conv(4) + bias + silu over xBC section of zx ----
__global__ __launch_bounds__(256) void conv_kernel(const unsigned short* __restrict__ zx,
                                                   const float* __restrict__ cw,
                                                   const float* __restrict__ cb,
                                                   unsigned short* __restrict__ xbc){
  int c = blockIdx.x * 256 + threadIdx.x;   // 0..2303
  int t = blockIdx.y;                        // 0..8191
  int l = t & (SEQL - 1);
  const unsigned short* base = zx + (size_t)t * LD_ZX + DI + c;
  float acc = cb[c];
  float w0 = cw[c*4+0], w1 = cw[c*4+1], w2 = cw[c*4+2], w3 = cw[c*4+3];
  if (l >= 3) acc += w0 * bf2f(*(base - 3 * LD_ZX));
  if (l >= 2) acc += w1 * bf2f(*(base - 2 * LD_ZX));
  if (l >= 1) acc += w2 * bf2f(*(base - 1 * LD_ZX));
  acc += w3 * bf2f(*base);
  float s = acc / (1.f + expf(-acc));        // silu
  xbc[(size_t)t * CONVD + c] = f2bf(s);
}

// ---- dt = softplus(dt_raw + bias); dA = exp(dt * -exp(A_log)) ----
__global__ __launch_bounds__(256) void dt_kernel(const unsigned short* __restrict__ zx,
                                                 const float* __restrict__ dtbias,
                                                 const float* __restrict__ alog,
                                                 float* __restrict__ dtb,
                                                 float* __restrict__ dab){
  int i = blockIdx.x * 256 + threadIdx.x;    // T*32
  int t = i >> 5, h = i & 31;
  float xr = bf2f(zx[(size_t)t * LD_ZX + 4352 + h]) + dtbias[h];
  float dt = (xr > 20.f) ? xr : log1pf(expf(xr));
  float A = -expf(alog[h]);
  dtb[i] = dt;
  dab[i] = expf(dt * A);
}

// ---- sequential SSM scan, LDS-windowed, p split 4-way for TLP ----
// 512 blocks = (b, h, pb); 256 thr = (pj 0..15) x (q 0..15); 8 states/thr.
__global__ __launch_bounds__(256) void scan_kernel(const unsigned short* __restrict__ xbc,
                                                   const float* __restrict__ dtb,
                                                   const float* __restrict__ dab,
                                                   const float* __restrict__ Dvec,
                                                   unsigned short* __restrict__ yout){
  __shared__ unsigned short Bb[2][SW * 128];
  __shared__ unsigned short Cb[2][SW * 128];
  __shared__ unsigned short Xb[2][SW * 16];
  __shared__ float DTb[2][64], DAb[2][64];   // 64-padded (gl_lds4 writes 64 lanes)

  const int blk = blockIdx.x;                // 4b x 32h x 4pb
  const int b = blk >> 7, h = (blk >> 2) & 31, pb = blk & 3;
  const int p0 = pb * 16;
  const int tid = threadIdx.x;
  const int wv = tid >> 6, l = tid & 63;
  const int pj = tid >> 4;            // 0..15
  const int q  = tid & 15;            // 0..15
  const int n0 = q * 8;
  const size_t tokBase = (size_t)b * SEQL;

  const unsigned short* gB = xbc + tokBase * CONVD + DI;
  const unsigned short* gX = xbc + tokBase * CONVD + h * HD + p0;
  const float* gdt = dtb + tokBase * NH + h;
  const float* gda = dab + tokBase * NH + h;

  auto stage = [&](int bi, int w){
    const int t0 = w * SW;
    // B, C windows: SW x 128 bf16 = 8 KB each = 8 chunks of 1 KB; wave wv -> 2 chunks
    #pragma unroll
    for (int i = 0; i < 2; ++i){
      const int c = wv * 2 + i;
      const size_t row = (size_t)(t0 + c * 4 + (l >> 4)) * CONVD + ((l & 15) << 3);
      gl_lds16(gB + row,          &Bb[bi][c * 512]);
      gl_lds16(gB + DSTATE + row, &Cb[bi][c * 512]);
    }
    // x window: SW tokens x 16 p = 1 KB; lane l -> token t0+(l>>1), p-half l&1
    if (wv == 0){
      const size_t xo = (size_t)(t0 + (l >> 1)) * CONVD + ((l & 1) << 3);
      gl_lds16(gX + xo, &Xb[bi][0]);
    }
    // dt / dA scalars (lanes beyond window clamp; surplus lanes write unused slots)
    int tc = t0 + l; if (tc > SEQL - 1) tc = SEQL - 1;
    if (wv == 1) gl_lds4(gdt + (size_t)tc * NH, &DTb[bi][0]);
    if (wv == 2) gl_lds4(gda + (size_t)tc * NH, &DAb[bi][0]);
  };

  float st[8];
  #pragma unroll
  for (int j = 0; j < 8; ++j) st[j] = 0.f;
  const float Dh = Dvec[h];

  stage(0, 0);
  __syncthreads();

  for (int w = 0; w < SEQL / SW; ++w){
    const int cur = w & 1;
    if (w + 1 < SEQL / SW) stage(cur ^ 1, w + 1);   // issue next window, don't wait
    const int t0 = w * SW;

    s16x8 B0 = *(const s16x8*)&Bb[cur][n0];
    s16x8 C0 = *(const s16x8*)&Cb[cur][n0];
    float xv  = bf2f(Xb[cur][pj]);
    float dtv = DTb[cur][0], dAv = DAb[cur][0];

    #pragma unroll 2
    for (int s = 0; s < SW; ++s){
      s16x8 nB0, nC0; float nx = 0.f, ndt = 0.f, ndA = 0.f;
      const bool hasNext = (s + 1 < SW);
      if (hasNext){
        const int o = (s + 1) * 128 + n0;
        nB0 = *(const s16x8*)&Bb[cur][o];
        nC0 = *(const s16x8*)&Cb[cur][o];
        nx  = bf2f(Xb[cur][(s + 1) * 16 + pj]);
        ndt = DTb[cur][s + 1];
        ndA = DAb[cur][s + 1];
      }

      float c1 = dtv * xv;
      float accp = 0.f;
      #pragma unroll
      for (int j = 0; j < 8; ++j){
        float bj = bf2f((unsigned short)B0[j]);
        float cj = bf2f((unsigned short)C0[j]);
        st[j] = fmaf(st[j], dAv, c1 * bj);
        accp = fmaf(st[j], cj, accp);
      }
      accp += __shfl_xor(accp, 1);
      accp += __shfl_xor(accp, 2);
      accp += __shfl_xor(accp, 4);
      accp += __shfl_xor(accp, 8);
      if (q == 0)
        yout[(tokBase + t0 + s) * DI + h * HD + p0 + pj] = f2bf(accp + Dh * xv);

      if (hasNext){
        B0 = nB0; C0 = nC0;
        xv = nx; dtv = ndt; dAv = ndA;
      }
    }
    __syncthreads();     // all waves done with buf[cur]; next window drained
  }
}

// ---- gated RMSNorm: out = gw * normalize(y * silu(z)); safe in-place on y ----
__global__ __launch_bounds__(256) void gated_kernel(const unsigned short* __restrict__ y,
                                                    const unsigned short* __restrict__ zx,
                                                    const float* __restrict__ gw,
                                                    unsigned short* __restrict__ out){
  int t = blockIdx.x, tid = threadIdx.x;
  s16x8 yv = *(const s16x8*)(y  + (size_t)t * DI    + tid * 8);
  s16x8 zv = *(const s16x8*)(zx + (size_t)t * LD_ZX + tid * 8);
  float g[8]; float ss = 0.f;
  #pragma unroll
  for (int j = 0; j < 8; ++j){
    float yf = bf2f((unsigned short)yv[j]);
    float zf = bf2f((unsigned short)zv[j]);
    float gi = yf * (zf / (1.f + expf(-zf)));
    g[j] = gi; ss += gi * gi;
  }
  #pragma unroll
  for (int o = 32; o; o >>= 1) ss += __shfl_down(ss, o);
  __shared__ float red[4];
  int wv = tid >> 6, lane = tid & 63;
  if (!lane) red[wv] = ss;
  __syncthreads();
  float tot = red[0] + red[1] + red[2] + red[3];
  float sc = rsqrtf(tot * (1.f/2048.f) + 1e-5f);
  unsigned short* o0 = out + (size_t)t * DI + tid * 8;
  #pragma unroll
  for (int j = 0; j < 8; ++j) o0[j] = f2bf(g[j] * sc * gw[tid * 8 + j]);
}

// ---- dec: output[t,v] = h_k[t,:] . dec_W[v,:] + dec_b[v]; one wave per dot ----
__global__ __launch_bounds__(256) void dec_kernel(const float* __restrict__ hk,
                                                  const float* __restrict__ dw,
                                                  const float* __restrict__ db,
                                                  float* __restrict__ out){
  int gwv = (blockIdx.x * 256 + threadIdx.x) >> 6;  // 0..24575
  int lane = threadIdx.x & 63;
  int t = gwv / 3, v = gwv - t * 3;
  const float* hr = hk + (size_t)t * DM + lane * 16;
  const float* wr = dw + v * DM + lane * 16;
  float acc = 0.f;
  #pragma unroll
  for (int j = 0; j < 16; ++j) acc = fmaf(hr[j], wr[j], acc);
  #pragma unroll
  for (int o = 32; o; o >>= 1) acc += __shfl_down(acc, o);
  if (!lane) out[t * 3 + v] = acc + db[v];
}

extern "C" void kernel_launch(void* const* d_in, const int* in_sizes, int n_in,
                              void* d_out, int out_size, void* d_ws, size_t ws_size,
                              hipStream_t stream){
  const float* h_prev    = (const float*)d_in[0];
  const float* emb_next  = (const float*)d_in[1];
  const float* norm_w    = (const float*)d_in[2];
  const float* proj_W    = (const float*)d_in[3];
  const float* proj_b    = (const float*)d_in[4];
  const float* in_proj_W = (const float*)d_in[5];
  const float* conv_w    = (const float*)d_in[6];
  const float* conv_b    = (const float*)d_in[7];
  const float* dt_bias   = (const float*)d_in[8];
  const float* A_log     = (const float*)d_in[9];
  const float* Dvec      = (const float*)d_in[10];
  const float* gnorm_w   = (const float*)d_in[11];
  const float* out_proj_W= (const float*)d_in[12];
  const float* dec_W     = (const float*)d_in[13];
  const float* dec_b     = (const float*)d_in[14];

  char* ws = (char*)d_ws;
  size_t off = 0;
  auto take = [&](size_t bytes){ char* p = ws + off; off += (bytes + 255) & ~(size_t)255; return p; };
  unsigned short* wproj = (unsigned short*)take((size_t)DM * DI * 2);
  unsigned short* winp  = (unsigned short*)take((size_t)LD_ZX * DM * 2);
  unsigned short* wout  = (unsigned short*)take((size_t)DM * DI * 2);
  unsigned short* zx    = (unsigned short*)take((size_t)T_TOK * LD_ZX * 2);
  float*          dtb   = (float*)take((size_t)T_TOK * NH * 4);
  float*          dab   = (float*)take((size_t)T_TOK * NH * 4);
  // region A: combined(32MB) + hprime(16MB); later overlaid by xbc(36MB)
  char* regionA = take((size_t)T_TOK * DI * 2 + (size_t)T_TOK * DM * 2);
  unsigned short* combined = (unsigned short*)regionA;
  unsigned short* hprime   = (unsigned short*)(regionA + (size_t)T_TOK * DI * 2);
  unsigned short* xbc      = (unsigned short*)regionA;           // overlays dead combined+hprime
  unsigned short* ybuf     = (unsigned short*)take((size_t)T_TOK * DI * 2);  // gated in-place

  float* outp = (float*)d_out;                   // [T*3] output, then [T*1024] h_k (f32)
  float* hk   = outp + (size_t)T_TOK * 3;

  // 1) weights -> bf16 (in_proj padded 4384->4480 rows with zeros)
  cvt_w_kernel<<<2048, 256, 0, stream>>>(proj_W, wproj, DM*DI/4, DM*DI/4);
  cvt_w_kernel<<<4480, 256, 0, stream>>>(in_proj_W, winp, LD_ZX*DM/4, DINP*DM/4);
  cvt_w_kernel<<<2048, 256, 0, stream>>>(out_proj_W, wout, DM*DI/4, DM*DI/4);

  // 2) dual rmsnorm -> combined (T x 2048)
  rmsnorm2_kernel<<<T_TOK, 256, 0, stream>>>(h_prev, emb_next, norm_w, combined);

  // 3) h_prime = combined @ proj_W^T + proj_b   (M=8192,N=1024,K=2048)
  gemm_bf16_kernel<false><<<(T_TOK/128)*(DM/128), 256, 0, stream>>>(combined, wproj, hprime, proj_b,
                                                                    T_TOK, DM, DI, DM);
  // 4) zxbcdt = h_prime @ in_proj_W^T           (M=8192,N=4480,K=1024)
  gemm_bf16_kernel<false><<<(T_TOK/128)*(LD_ZX/128), 256, 0, stream>>>(hprime, winp, zx, nullptr,
                                                                       T_TOK, LD_ZX, DM, LD_ZX);
  // 5) conv + silu on xBC  (xbc overlays combined/hprime which are now dead)
  conv_kernel<<<dim3(CONVD/256, T_TOK), 256, 0, stream>>>(zx, conv_w, conv_b, xbc);
  // 6) dt / dA
  dt_kernel<<<T_TOK*NH/256, 256, 0, stream>>>(zx, dt_bias, A_log, dtb, dab);
  // 7) SSM scan -> y (+ D*x), LDS-windowed, 512 blocks
  scan_kernel<<<512, 256, 0, stream>>>(xbc, dtb, dab, Dvec, ybuf);
  // 8) gated rmsnorm, in-place on ybuf
  gated_kernel<<<T_TOK, 256, 0, stream>>>(ybuf, zx, gnorm_w, ybuf);
  // 9) h_k = y_gated @ out_proj_W^T -> d_out[24576..] as f32  (M=8192,N=1024,K=2048)
  gemm_bf16_kernel<true><<<(T_TOK/128)*(DM/128), 256, 0, stream>>>(ybuf, wout, hk, nullptr,
                                                                   T_TOK, DM, DI, DM);
  // 10) output = h_k @ dec_W^T + dec_b -> d_out[0..24576) as f32
  dec_kernel<<<T_TOK*3/4, 256, 0, stream>>>(hk, dec_W, dec_b, outp);
}